// Round 6
// baseline (202.754 us; speedup 1.0000x reference)
//
#include <hip/hip_runtime.h>
#include <math.h>

#define DD 2048
#define EE 64
#define TM 32                 // tokens per block; grid = 512 -> 2 blocks/CU
#define BK 64                 // K per chunk (2 MFMA K-steps)
#define NCHUNK (DD / BK)      // 32 (even: loop unrolled by 2)
#define THREADS 512           // 8 waves/block -> 16 waves/CU

// LDS row layout: per 8-k group g: [hi(8 f16) 16B][lo(8 f16) 16B] at byte 32*g.
// ROWB = 8 groups * 32B + 16B pad = 272 -> bank step 4r+8g: b128 reads/writes
// spread 8-per-bank = the 128B/cyc minimum (conflict-free).
#define ROWB 272
#define XPLANE (TM * ROWB)        // 8704 B
#define WPLANE (EE * ROWB)        // 17408 B
#define BUFB   (XPLANE + WPLANE)  // 26112 B per buffer

typedef _Float16 f16x8 __attribute__((ext_vector_type(8)));
typedef float    f32x4 __attribute__((ext_vector_type(4)));

// lgkm-only barrier: drains LDS reads+writes (cross-wave visibility) but
// leaves global loads (wave-private reg dests) in flight across the barrier.
// asm memory clobber = compiler fence for DS ops; sched_barrier pins motion.
#define BARRIER() { asm volatile("s_waitcnt lgkmcnt(0)" ::: "memory"); \
                    __builtin_amdgcn_s_barrier(); \
                    __builtin_amdgcn_sched_barrier(0); }

// split 8 consecutive f32 (scaled by 32) into f16 hi + f16 lo planes
__device__ static inline void split8(const float4 a, const float4 b,
                                     f16x8& hi, f16x8& lo) {
    const float S = 32.f;     // keeps lo parts out of f16 subnormal flush range
    const float v[8] = {a.x * S, a.y * S, a.z * S, a.w * S,
                        b.x * S, b.y * S, b.z * S, b.w * S};
#pragma unroll
    for (int i = 0; i < 8; ++i) {
        const _Float16 h = (_Float16)v[i];
        hi[i] = h;
        lo[i] = (_Float16)(v[i] - (float)h);
    }
}

__global__ __launch_bounds__(THREADS, 4) void router_kernel(
    const float* __restrict__ x, const float* __restrict__ W,
    const float* __restrict__ bias_g, float* __restrict__ out, int n_tokens)
{
    __shared__ __attribute__((aligned(16))) char  lds[2 * BUFB];        // 52224 B
    __shared__ __attribute__((aligned(16))) float logits[TM * (EE + 1)]; // 8320 B

    const int tid   = threadIdx.x;
    const int tBase = blockIdx.x * TM;

    // ---- staging mapping: thread owns 8 consecutive k of one row ----
    const int sr = tid >> 3;          // row 0..63
    const int sg = tid & 7;           // k-group 0..7 (k = 8*sg .. 8*sg+7)
    const bool do_x = (sr < TM);      // waves 0..3 stage x too (wave-uniform)

    const float* xrow = x + (size_t)(tBase + (sr & (TM - 1))) * DD + sg * 8;
    const float* wrow = W + (size_t)sr * DD + sg * 8;

    // two register sets: chunk k lives in set[k&1]; loads for c+2 issue while
    // set holding c+1 is still unconsumed -> no WAR serialization
    float4 rxA0 = {0,0,0,0}, rxA1 = {0,0,0,0}, rwA0, rwA1;
    float4 rxB0 = {0,0,0,0}, rxB1 = {0,0,0,0}, rwB0, rwB1;

#define LOADS(c, rx0, rx1, rw0, rw1) { \
        rw0 = *(const float4*)&wrow[(c) * BK];       \
        rw1 = *(const float4*)&wrow[(c) * BK + 4];   \
        if (do_x) {                                  \
            rx0 = *(const float4*)&xrow[(c) * BK];   \
            rx1 = *(const float4*)&xrow[(c) * BK + 4]; } }

    // all LDS staging stores are single b128 (conflict-free 8/bank spread)
#define WRITE_STAGE(buf, rx0, rx1, rw0, rw1) { \
    char* base = lds + (size_t)(buf) * BUFB; \
    { f16x8 hi, lo; split8(rw0, rw1, hi, lo); \
      const int off = XPLANE + sr * ROWB + sg * 32; \
      *(f16x8*)(base + off)      = hi; \
      *(f16x8*)(base + off + 16) = lo; } \
    if (do_x) { f16x8 hi, lo; split8(rx0, rx1, hi, lo); \
      const int off = sr * ROWB + sg * 32; \
      *(f16x8*)(base + off)      = hi; \
      *(f16x8*)(base + off + 16) = lo; } }

    // ---- MFMA mapping (16x16x32 f16): wave = 16 tokens x 16 experts ----
    // A: lane holds A[row=l&15][k=(l>>4)*8+j]; C/D: col=l&15, row=(l>>4)*4+reg
    const int wv   = tid >> 6;        // wave 0..7
    const int lane = tid & 63;
    const int mt   = wv & 1;          // token tile
    const int nt   = wv >> 1;         // expert tile 0..3
    const int r16  = lane & 15;
    const int kg   = lane >> 4;

    const int aoff = (mt * 16 + r16) * ROWB + kg * 32;
    const int boff = XPLANE + (nt * 16 + r16) * ROWB + kg * 32;

    f32x4 acc = {0.f, 0.f, 0.f, 0.f};

    // 3-product split (skip lo*lo: ~2^-22 rel, negligible)
#define COMPUTE(buf) { \
    const char* base = lds + (size_t)(buf) * BUFB; \
    _Pragma("unroll") for (int ks = 0; ks < 2; ++ks) { \
        const f16x8 ah = *(const f16x8*)(base + aoff + ks * 128); \
        const f16x8 al = *(const f16x8*)(base + aoff + ks * 128 + 16); \
        const f16x8 bh = *(const f16x8*)(base + boff + ks * 128); \
        const f16x8 bl = *(const f16x8*)(base + boff + ks * 128 + 16); \
        acc = __builtin_amdgcn_mfma_f32_16x16x32_f16(ah, bh, acc, 0, 0, 0); \
        acc = __builtin_amdgcn_mfma_f32_16x16x32_f16(al, bh, acc, 0, 0, 0); \
        acc = __builtin_amdgcn_mfma_f32_16x16x32_f16(ah, bl, acc, 0, 0, 0); \
    } }

    // ---- pipeline: 1 lgkm-barrier/chunk, loads 2-deep, vmcnt never drained --
    LOADS(0, rxA0, rxA1, rwA0, rwA1);
    WRITE_STAGE(0, rxA0, rxA1, rwA0, rwA1);   // dep-wait on A's loads
    LOADS(1, rxB0, rxB1, rwB0, rwB1);

    for (int c = 0; c < NCHUNK; c += 2) {
        BARRIER();                              // buf0 visible; buf1 free
        if (c + 2 < NCHUNK) LOADS(c + 2, rxA0, rxA1, rwA0, rwA1);
        COMPUTE(0);                             // chunk c
        WRITE_STAGE(1, rxB0, rxB1, rwB0, rwB1); // chunk c+1 (counted vmcnt)

        BARRIER();                              // buf1 visible; buf0 free
        if (c + 3 < NCHUNK) LOADS(c + 3, rxB0, rxB1, rwB0, rwB1);
        COMPUTE(1);                             // chunk c+1
        if (c + 2 < NCHUNK)
            WRITE_STAGE(0, rxA0, rxA1, rwA0, rwA1); // chunk c+2
    }

    // ---- epilogue: unscale (acc = 1024 * logit), add bias, top-2 ----
    __syncthreads();
    const int col  = nt * 16 + r16;
    const float bcol = bias_g[col];
    const float INV  = 1.f / 1024.f;
    const int rbase  = mt * 16 + kg * 4;
#pragma unroll
    for (int r = 0; r < 4; ++r)
        logits[(rbase + r) * (EE + 1) + col] = acc[r] * INV + bcol;
    __syncthreads();

    if (tid < TM) {
        const float* lrow = &logits[tid * (EE + 1)];
        float v1 = -INFINITY, v2 = -INFINITY;
        int   i1 = 0, i2 = 0;
        for (int e = 0; e < EE; ++e) {
            const float v = lrow[e];
            if (v > v1) { v2 = v1; i2 = i1; v1 = v; i1 = e; }
            else if (v > v2) { v2 = v; i2 = e; }
        }
        const float ed  = expf(v2 - v1);
        const float inv = 1.f / (1.f + ed);
        const int tok = tBase + tid;
        out[tok * 2 + 0] = inv;
        out[tok * 2 + 1] = ed * inv;
        float* oidx = out + (size_t)2 * n_tokens;
        oidx[tok * 2 + 0] = (float)i1;
        oidx[tok * 2 + 1] = (float)i2;
    }
}

extern "C" void kernel_launch(void* const* d_in, const int* in_sizes, int n_in,
                              void* d_out, int out_size, void* d_ws, size_t ws_size,
                              hipStream_t stream) {
    const float* x = (const float*)d_in[0];
    const float* W = (const float*)d_in[1];
    const float* b = (const float*)d_in[2];
    float* out = (float*)d_out;

    const int n_tokens = in_sizes[0] / DD;      // 16384
    const int n_blocks = n_tokens / TM;         // 512

    router_kernel<<<n_blocks, THREADS, 0, stream>>>(x, W, b, out, n_tokens);
}